// Round 1
// baseline (6422.336 us; speedup 1.0000x reference)
//
#include <hip/hip_runtime.h>

// PressureProjection on MI355X.
// Pipeline per launch (same work every call; graph-capture safe):
//  1. memsetAsync zero region (cnt/divacc/diag/scalar slots)
//  2. edge_pass1: flux->divacc[dst], w->diag[dst], cnt[dst]++ (atomics, once)
//  3. 3-kernel exclusive scan of cnt -> CSR offsets
//  4. scatter_edges: bucket edges by dst (csr_src, csr_w, csr_eid)
//  5. node_setup: b=div, r0=b, minv, p0, rz[0], rr[0]
//  6. 20x { matvec(+pAp dot), cg_update(+rz/rr dots), p_update }
//  7. finalize: grad_phi via CSR gather, write u_corrected + phi
// Scalars live in per-iteration slots so no mid-graph re-zeroing is needed.

#define TPB 256
#define CG_ITERS 20
#define TOL2 1e-8f   // (CG_TOL=1e-4)^2

__device__ inline void block_reduce1_atomic(float v1, float* d1) {
#pragma unroll
  for (int o = 32; o; o >>= 1) v1 += __shfl_down(v1, o, 64);
  __shared__ float s1[TPB / 64];
  int lane = threadIdx.x & 63, wid = threadIdx.x >> 6;
  if (lane == 0) s1[wid] = v1;
  __syncthreads();
  if (threadIdx.x == 0) {
    float t1 = 0.f;
#pragma unroll
    for (int k = 0; k < TPB / 64; k++) t1 += s1[k];
    atomicAdd(d1, t1);
  }
}

__device__ inline void block_reduce2_atomic(float v1, float v2, float* d1, float* d2) {
#pragma unroll
  for (int o = 32; o; o >>= 1) {
    v1 += __shfl_down(v1, o, 64);
    v2 += __shfl_down(v2, o, 64);
  }
  __shared__ float s1[TPB / 64], s2[TPB / 64];
  int lane = threadIdx.x & 63, wid = threadIdx.x >> 6;
  if (lane == 0) { s1[wid] = v1; s2[wid] = v2; }
  __syncthreads();
  if (threadIdx.x == 0) {
    float t1 = 0.f, t2 = 0.f;
#pragma unroll
    for (int k = 0; k < TPB / 64; k++) { t1 += s1[k]; t2 += s2[k]; }
    atomicAdd(d1, t1);
    atomicAdd(d2, t2);
  }
}

// ---- one-time edge pass: divergence accum, diag accum, histogram ----
__global__ __launch_bounds__(TPB) void edge_pass1(
    const int* __restrict__ ei, const float* __restrict__ u_hat,
    const float* __restrict__ fn, const float* __restrict__ fa,
    const float* __restrict__ fd, float* __restrict__ divacc,
    float* __restrict__ diag, unsigned* __restrict__ cnt, int E) {
  int e = blockIdx.x * TPB + threadIdx.x;
  if (e >= E) return;
  int s = ei[e], d = ei[E + e];
  float ux = 0.5f * (u_hat[3 * s]     + u_hat[3 * d]);
  float uy = 0.5f * (u_hat[3 * s + 1] + u_hat[3 * d + 1]);
  float uz = 0.5f * (u_hat[3 * s + 2] + u_hat[3 * d + 2]);
  float area = fa[e];
  float flux = (ux * fn[3 * e] + uy * fn[3 * e + 1] + uz * fn[3 * e + 2]) * area;
  float w = area / fmaxf(fd[e], 1e-8f);
  atomicAdd(&divacc[d], flux);
  atomicAdd(&diag[d], w);
  atomicAdd(&cnt[d], 1u);
}

// ---- scan (1024 elems / block) ----
__global__ __launch_bounds__(TPB) void scan_blocks(
    const unsigned* __restrict__ cnt, unsigned* __restrict__ offs,
    unsigned* __restrict__ btot, int n) {
  __shared__ unsigned sd[TPB];
  int t = threadIdx.x;
  int base = blockIdx.x * 1024 + t * 4;
  unsigned v0 = 0, v1 = 0, v2 = 0, v3 = 0;
  if (base + 0 < n) v0 = cnt[base + 0];
  if (base + 1 < n) v1 = cnt[base + 1];
  if (base + 2 < n) v2 = cnt[base + 2];
  if (base + 3 < n) v3 = cnt[base + 3];
  unsigned local = v0 + v1 + v2 + v3;
  sd[t] = local;
  __syncthreads();
  for (int o = 1; o < TPB; o <<= 1) {
    unsigned x = (t >= o) ? sd[t - o] : 0u;
    __syncthreads();
    sd[t] += x;
    __syncthreads();
  }
  unsigned excl = sd[t] - local;
  if (base + 0 < n) offs[base + 0] = excl; excl += v0;
  if (base + 1 < n) offs[base + 1] = excl; excl += v1;
  if (base + 2 < n) offs[base + 2] = excl; excl += v2;
  if (base + 3 < n) offs[base + 3] = excl;
  if (t == TPB - 1) btot[blockIdx.x] = sd[TPB - 1];
}

__global__ __launch_bounds__(512) void scan_totals(unsigned* __restrict__ btot, int nb) {
  __shared__ unsigned sd[512];
  int t = threadIdx.x;
  unsigned v = (t < nb) ? btot[t] : 0u;
  sd[t] = v;
  __syncthreads();
  for (int o = 1; o < 512; o <<= 1) {
    unsigned x = (t >= o) ? sd[t - o] : 0u;
    __syncthreads();
    sd[t] += x;
    __syncthreads();
  }
  if (t < nb) btot[t] = sd[t] - v;  // exclusive
}

__global__ __launch_bounds__(TPB) void scan_add(
    unsigned* __restrict__ offs, unsigned* __restrict__ wp,
    const unsigned* __restrict__ btot, int n, unsigned total) {
  int i = blockIdx.x * TPB + threadIdx.x;
  if (i < n) {
    unsigned v = offs[i] + btot[i >> 10];
    offs[i] = v;
    wp[i] = v;
  }
  if (i == 0) offs[n] = total;
}

// ---- bucket edges by dst ----
__global__ __launch_bounds__(TPB) void scatter_edges(
    const int* __restrict__ ei, const float* __restrict__ fa,
    const float* __restrict__ fd, unsigned* __restrict__ wp,
    int* __restrict__ csr_src, float* __restrict__ csr_w,
    int* __restrict__ csr_eid, int E) {
  int e = blockIdx.x * TPB + threadIdx.x;
  if (e >= E) return;
  int s = ei[e], d = ei[E + e];
  float w = fa[e] / fmaxf(fd[e], 1e-8f);
  unsigned pos = atomicAdd(&wp[d], 1u);
  csr_src[pos] = s;
  csr_w[pos] = w;
  csr_eid[pos] = e;
}

// ---- CG setup: b = div, r0 = b, z0 = minv*b, p0 = z0, rz0, rr0 ----
__global__ __launch_bounds__(TPB) void node_setup(
    const float* __restrict__ divacc, const float* __restrict__ diag,
    const float* __restrict__ cv, float* __restrict__ r, float* __restrict__ p,
    float* __restrict__ phi, float* __restrict__ minv,
    float* __restrict__ rz0, float* __restrict__ rr0, int N) {
  int i = blockIdx.x * TPB + threadIdx.x;
  float rzv = 0.f, rrv = 0.f;
  if (i < N) {
    float vol = fmaxf(cv[i], 1e-12f);
    float b = divacc[i] / vol;
    float mi = 1.0f / fmaxf(diag[i], 1e-8f);
    minv[i] = mi;
    r[i] = b;
    phi[i] = 0.f;
    float pi = mi * b;
    p[i] = pi;
    rzv = b * pi;
    rrv = b * b;
  }
  block_reduce2_atomic(rzv, rrv, rz0, rr0);
}

// ---- ap = diag*p - sum_j w_j * p[src_j]; pAp += p.ap ----
__global__ __launch_bounds__(TPB) void matvec(
    const float* __restrict__ p, const float* __restrict__ diag,
    const unsigned* __restrict__ offs, const int* __restrict__ csr_src,
    const float* __restrict__ csr_w, float* __restrict__ ap,
    float* __restrict__ pap_slot, int N) {
  int i = blockIdx.x * TPB + threadIdx.x;
  float contrib = 0.f;
  if (i < N) {
    float pi = p[i];
    float sum = diag[i] * pi;
    unsigned a = offs[i], b = offs[i + 1];
    for (unsigned j = a; j < b; j++) sum -= csr_w[j] * p[csr_src[j]];
    ap[i] = sum;
    contrib = pi * sum;
  }
  block_reduce1_atomic(contrib, pap_slot);
}

// ---- gated phi/r update + rz/rr dots for next iter ----
__global__ __launch_bounds__(TPB) void cg_update(
    float* __restrict__ phi, float* __restrict__ r, const float* __restrict__ p,
    const float* __restrict__ ap, const float* __restrict__ minv,
    const float* __restrict__ rz_it, const float* __restrict__ pap_it,
    const float* __restrict__ rr_it, float* __restrict__ rz_next,
    float* __restrict__ rr_next, int N) {
  int i = blockIdx.x * TPB + threadIdx.x;
  float rzv = 0.f, rrv = 0.f;
  if (i < N) {
    bool act = (*rr_it >= TOL2);
    float alpha = (*rz_it) / ((*pap_it) + 1e-12f);
    float ri = r[i];
    if (act) {
      phi[i] += alpha * p[i];
      ri -= alpha * ap[i];
      r[i] = ri;
    }
    float zi = minv[i] * ri;
    rzv = ri * zi;
    rrv = ri * ri;
  }
  block_reduce2_atomic(rzv, rrv, rz_next, rr_next);
}

// ---- gated p = z + beta*p ----
__global__ __launch_bounds__(TPB) void p_update(
    float* __restrict__ p, const float* __restrict__ r,
    const float* __restrict__ minv, const float* __restrict__ rz_next,
    const float* __restrict__ rz_it, const float* __restrict__ rr_it, int N) {
  int i = blockIdx.x * TPB + threadIdx.x;
  if (i >= N) return;
  if (*rr_it >= TOL2) {
    float beta = (*rz_next) / ((*rz_it) + 1e-12f);
    p[i] = minv[i] * r[i] + beta * p[i];
  }
}

// ---- pressure correction + output ----
__global__ __launch_bounds__(TPB) void finalize(
    const float* __restrict__ u_hat, const float* __restrict__ cv,
    const float* __restrict__ phi, const unsigned* __restrict__ offs,
    const int* __restrict__ csr_src, const float* __restrict__ csr_w,
    const int* __restrict__ csr_eid, const float* __restrict__ fn,
    float* __restrict__ out, int N) {
  int i = blockIdx.x * TPB + threadIdx.x;
  if (i >= N) return;
  float gx = 0.f, gy = 0.f, gz = 0.f;
  unsigned a = offs[i], b = offs[i + 1];
  for (unsigned j = a; j < b; j++) {
    float t = csr_w[j] * phi[csr_src[j]];
    int e = csr_eid[j];
    gx += t * fn[3 * e];
    gy += t * fn[3 * e + 1];
    gz += t * fn[3 * e + 2];
  }
  float iv = 1.0f / fmaxf(cv[i], 1e-12f);
  out[3 * i]     = u_hat[3 * i]     - gx * iv;
  out[3 * i + 1] = u_hat[3 * i + 1] - gy * iv;
  out[3 * i + 2] = u_hat[3 * i + 2] - gz * iv;
  out[3 * N + i] = phi[i];
}

extern "C" void kernel_launch(void* const* d_in, const int* in_sizes, int n_in,
                              void* d_out, int out_size, void* d_ws, size_t ws_size,
                              hipStream_t stream) {
  const float* u_hat = (const float*)d_in[0];
  const int*   ei    = (const int*)d_in[1];
  const float* fn    = (const float*)d_in[2];
  const float* fa    = (const float*)d_in[3];
  const float* fd    = (const float*)d_in[4];
  const float* cv    = (const float*)d_in[5];
  float* out = (float*)d_out;

  const int N = in_sizes[0] / 3;   // 500,000
  const int E = in_sizes[1] / 2;   // 8,000,000

  // ---- workspace bump allocator (256B aligned) ----
  char* base = (char*)d_ws;
  size_t off = 0;
  auto alloc = [&](size_t bytes) -> void* {
    void* ptr = base + off;
    off = (off + bytes + 255) & ~size_t(255);
    return ptr;
  };
  // zero region first (one memset covers all of it)
  unsigned* cnt    = (unsigned*)alloc((size_t)N * 4);
  float*    divacc = (float*)alloc((size_t)N * 4);
  float*    diag   = (float*)alloc((size_t)N * 4);
  float*    scal   = (float*)alloc(512);  // rz[21] | rr[21] | pAp[20]
  size_t zero_bytes = off;
  float* rz  = scal;       // 21 slots
  float* rr  = scal + 32;  // 21 slots
  float* pap = scal + 64;  // 20 slots
  // non-zeroed scratch
  unsigned* offs    = (unsigned*)alloc((size_t)(N + 1) * 4);
  unsigned* wp      = (unsigned*)alloc((size_t)N * 4);
  unsigned* btot    = (unsigned*)alloc(512 * 4);
  float*    minv    = (float*)alloc((size_t)N * 4);
  float*    phi     = (float*)alloc((size_t)N * 4);
  float*    rvec    = (float*)alloc((size_t)N * 4);
  float*    pvec    = (float*)alloc((size_t)N * 4);
  float*    ap      = (float*)alloc((size_t)N * 4);
  int*      csr_src = (int*)alloc((size_t)E * 4);
  float*    csr_w   = (float*)alloc((size_t)E * 4);
  int*      csr_eid = (int*)alloc((size_t)E * 4);
  (void)ws_size; (void)n_in; (void)out_size;

  const int gridE = (E + TPB - 1) / TPB;
  const int gridN = (N + TPB - 1) / TPB;
  const int nbScan = (N + 1023) / 1024;  // <= 512

  hipMemsetAsync(base, 0, zero_bytes, stream);

  edge_pass1<<<gridE, TPB, 0, stream>>>(ei, u_hat, fn, fa, fd, divacc, diag, cnt, E);

  scan_blocks<<<nbScan, TPB, 0, stream>>>(cnt, offs, btot, N);
  scan_totals<<<1, 512, 0, stream>>>(btot, nbScan);
  scan_add<<<gridN, TPB, 0, stream>>>(offs, wp, btot, N, (unsigned)E);

  scatter_edges<<<gridE, TPB, 0, stream>>>(ei, fa, fd, wp, csr_src, csr_w, csr_eid, E);

  node_setup<<<gridN, TPB, 0, stream>>>(divacc, diag, cv, rvec, pvec, phi, minv,
                                        &rz[0], &rr[0], N);

  for (int it = 0; it < CG_ITERS; it++) {
    matvec<<<gridN, TPB, 0, stream>>>(pvec, diag, offs, csr_src, csr_w, ap,
                                      &pap[it], N);
    cg_update<<<gridN, TPB, 0, stream>>>(phi, rvec, pvec, ap, minv,
                                         &rz[it], &pap[it], &rr[it],
                                         &rz[it + 1], &rr[it + 1], N);
    if (it < CG_ITERS - 1) {
      p_update<<<gridN, TPB, 0, stream>>>(pvec, rvec, minv,
                                          &rz[it + 1], &rz[it], &rr[it], N);
    }
  }

  finalize<<<gridN, TPB, 0, stream>>>(u_hat, cv, phi, offs, csr_src, csr_w,
                                      csr_eid, fn, out, N);
}